// Round 1
// baseline (505.593 us; speedup 1.0000x reference)
//
#include <hip/hip_runtime.h>

namespace {
constexpr int LN = 6 * 256;  // 1536 independent (l,n) problems
constexpr int Q = 64;
constexpr int C = 256;
constexpr float EPS_DEN = 1e-7f;
constexpr float EPS_SQRT = 1e-12f;

// DPP row rotate-add: butterfly reduce within a 16-lane row (VALU pipe, no LDS)
template <int CTRL>
__device__ __forceinline__ float ror_add(float v) {
  int r = __builtin_amdgcn_mov_dpp(__float_as_int(v), CTRL, 0xF, 0xF, true);
  return v + __int_as_float(r);
}
__device__ __forceinline__ float row_reduce16(float v) {
  v = ror_add<0x128>(v);  // row_ror:8
  v = ror_add<0x124>(v);  // row_ror:4
  v = ror_add<0x122>(v);  // row_ror:2
  v = ror_add<0x121>(v);  // row_ror:1
  return v;               // all 16 lanes hold the row sum
}
}  // namespace

__global__ __launch_bounds__(256, 2) void kmeans_em_kernel(
    const float* __restrict__ hs, const float* __restrict__ cen_in,
    float* __restrict__ out) {
  const int bid = blockIdx.x;
  const int tid = threadIdx.x;
  const int cg = tid & 15;  // channel-group within 16-lane row
  const int qg = tid >> 4;  // q-group (16 groups of 4 q's)
  const int wv = tid >> 6;

  const float* __restrict__ hsb = hs + (size_t)bid * (Q * C);

  __shared__ __align__(16) float cen_lds[2 * C];
  __shared__ __align__(16) float a_lds[Q * 2];
  __shared__ __align__(16) float denp[8];

  // ---- hsD: thread = channel, all 64 q (for num = a^T * hs, no reduction)
  float hsD[Q];
#pragma unroll
  for (int q = 0; q < Q; ++q) hsD[q] = hsb[q * C + tid];

  // ---- hsB: rows qg*4+j, channels cg*16 .. +15 (for xc = hs * cen^T)
  float4 hsB[4][4];
#pragma unroll
  for (int j = 0; j < 4; ++j)
#pragma unroll
    for (int jj = 0; jj < 4; ++jj)
      hsB[j][jj] = *reinterpret_cast<const float4*>(
          &hsb[(qg * 4 + j) * C + cg * 16 + jj * 4]);

  // ---- x2 per q-row (computed once; row-uniform after reduce)
  float x2q[4];
#pragma unroll
  for (int j = 0; j < 4; ++j) {
    float s = 0.f;
#pragma unroll
    for (int jj = 0; jj < 4; ++jj) {
      float4 h = hsB[j][jj];
      s += h.x * h.x + h.y * h.y + h.z * h.z + h.w * h.w;
    }
    x2q[j] = row_reduce16(s);
  }

  // ---- initial centers (thread = channel)
  float cen0 = cen_in[(size_t)bid * 2 * C + tid];
  float cen1 = cen_in[(size_t)bid * 2 * C + C + tid];

  // swizzled float position: chunk n=tid>>2 stored at slot ((n&3)<<4)|(n>>2)
  const int swz = ((((tid >> 2) & 3) << 4) | (tid >> 4)) * 4 + (tid & 3);
  cen_lds[swz] = cen0;
  cen_lds[C + swz] = cen1;
  __syncthreads();

  const float4* cen4 = reinterpret_cast<const float4*>(cen_lds);
  const float4* a4 = reinterpret_cast<const float4*>(a_lds);

  float aq[4][2];

#pragma unroll 1
  for (int it = 0; it < Q; ++it) {
    // ---- phase B: xc = hs . cen (per-thread partial over 16 channels)
    float4 ck0[4], ck1[4];
#pragma unroll
    for (int jj = 0; jj < 4; ++jj) {
      ck0[jj] = cen4[(jj << 4) | cg];
      ck1[jj] = cen4[64 + ((jj << 4) | cg)];
    }
    float c2p0 = 0.f, c2p1 = 0.f;
    float acc[4][2] = {{0.f, 0.f}, {0.f, 0.f}, {0.f, 0.f}, {0.f, 0.f}};
#pragma unroll
    for (int jj = 0; jj < 4; ++jj) {
      c2p0 += ck0[jj].x * ck0[jj].x + ck0[jj].y * ck0[jj].y +
              ck0[jj].z * ck0[jj].z + ck0[jj].w * ck0[jj].w;
      c2p1 += ck1[jj].x * ck1[jj].x + ck1[jj].y * ck1[jj].y +
              ck1[jj].z * ck1[jj].z + ck1[jj].w * ck1[jj].w;
#pragma unroll
      for (int j = 0; j < 4; ++j) {
        float4 h = hsB[j][jj];
        acc[j][0] += h.x * ck0[jj].x + h.y * ck0[jj].y + h.z * ck0[jj].z +
                     h.w * ck0[jj].w;
        acc[j][1] += h.x * ck1[jj].x + h.y * ck1[jj].y + h.z * ck1[jj].z +
                     h.w * ck1[jj].w;
      }
    }
    const float c2_0 = row_reduce16(c2p0);
    const float c2_1 = row_reduce16(c2p1);

    // ---- phase C: distances -> softmax over k=2 (row-uniform, all lanes)
    float dp0 = 0.f, dp1 = 0.f;
#pragma unroll
    for (int j = 0; j < 4; ++j) {
      float xc0 = row_reduce16(acc[j][0]);
      float xc1 = row_reduce16(acc[j][1]);
      float d0 = fmaxf(x2q[j] + c2_0 - 2.f * xc0, EPS_SQRT);
      float d1 = fmaxf(x2q[j] + c2_1 - 2.f * xc1, EPS_SQRT);
      float t0 = sqrtf(d0);
      float t1 = sqrtf(d1);
      float m = fminf(t0, t1);  // = -max(-t0,-t1)
      float e0 = __expf(m - t0);
      float e1 = __expf(m - t1);
      float inv = 1.f / (e0 + e1);
      aq[j][0] = e0 * inv;
      aq[j][1] = e1 * inv;
      dp0 += aq[j][0];
      dp1 += aq[j][1];
    }
    if (cg == 0) {  // one writer per row; values are row-uniform
      *reinterpret_cast<float4*>(&a_lds[qg * 8]) =
          make_float4(aq[0][0], aq[0][1], aq[1][0], aq[1][1]);
      *reinterpret_cast<float4*>(&a_lds[qg * 8 + 4]) =
          make_float4(aq[2][0], aq[2][1], aq[3][0], aq[3][1]);
    }
    // den partial for this wave's 16 q (reduce across the 4 rows)
    dp0 += __shfl_xor(dp0, 16);
    dp0 += __shfl_xor(dp0, 32);
    dp1 += __shfl_xor(dp1, 16);
    dp1 += __shfl_xor(dp1, 32);
    if ((tid & 63) == 0) {
      denp[wv * 2] = dp0;
      denp[wv * 2 + 1] = dp1;
    }
    __syncthreads();

    // ---- phase D: num[k][c] = sum_q a[q][k] * hs[q][c]  (thread = channel)
    float4 dv0 = *reinterpret_cast<const float4*>(&denp[0]);
    float4 dv1 = *reinterpret_cast<const float4*>(&denp[4]);
    float den0 = dv0.x + dv0.z + dv1.x + dv1.z;
    float den1 = dv0.y + dv0.w + dv1.y + dv1.w;

    float num0 = 0.f, num1 = 0.f;
#pragma unroll
    for (int qq = 0; qq < 32; ++qq) {
      float4 av = a4[qq];  // uniform address: broadcast, conflict-free
      num0 += av.x * hsD[2 * qq];
      num1 += av.y * hsD[2 * qq];
      num0 += av.z * hsD[2 * qq + 1];
      num1 += av.w * hsD[2 * qq + 1];
    }
    cen0 = num0 / (den0 + EPS_DEN);
    cen1 = num1 / (den1 + EPS_DEN);
    cen_lds[swz] = cen0;
    cen_lds[C + swz] = cen1;
    __syncthreads();
  }

  // ---- outputs: centers [*,2,C] then assignment [*,Q,2]
  float* __restrict__ outc = out + (size_t)bid * 2 * C;
  outc[tid] = cen0;
  outc[C + tid] = cen1;
  float* __restrict__ outa = out + (size_t)LN * 2 * C + (size_t)bid * Q * 2;
  if (tid < Q * 2) outa[tid] = a_lds[tid];
}

extern "C" void kernel_launch(void* const* d_in, const int* in_sizes, int n_in,
                              void* d_out, int out_size, void* d_ws,
                              size_t ws_size, hipStream_t stream) {
  const float* hs = (const float*)d_in[0];
  const float* cen = (const float*)d_in[1];
  float* out = (float*)d_out;
  hipLaunchKernelGGL(kmeans_em_kernel, dim3(LN), dim3(256), 0, stream, hs, cen,
                     out);
}

// Round 2
// 173.335 us; speedup vs baseline: 2.9169x; 2.9169x over previous
//
#include <hip/hip_runtime.h>

namespace {
constexpr int PB = 6 * 256;  // 1536 independent (l,n) problems
constexpr int Q = 64;
constexpr int C = 256;
constexpr float EPS_DEN = 1e-7f;
constexpr float EPS_SQRT = 1e-12f;
constexpr int GT_FLOATS = Q * Q;   // 4096 per problem (packed transposed)
constexpr int AUX_FLOATS = 256;    // xc0[64][2] | x2[64] | c2 partials[8]

__device__ __forceinline__ float wave_sum64(float v) {
  v += __shfl_xor(v, 1);
  v += __shfl_xor(v, 2);
  v += __shfl_xor(v, 4);
  v += __shfl_xor(v, 8);
  v += __shfl_xor(v, 16);
  v += __shfl_xor(v, 32);
  return v;
}
}  // namespace

// ---------------- kernel 1: G = hs hs^T, x2 = diag(G), xc0 = hs.cen0, c2_0
__global__ __launch_bounds__(256, 2) void k1_gram(
    const float* __restrict__ hs, const float* __restrict__ cen,
    float* __restrict__ ws) {
  const int prob = blockIdx.x;
  const int tid = threadIdx.x;
  const int lane = tid & 63, wv = tid >> 6;

  __shared__ __align__(16) float hsl[Q * C];  // 64 KiB, XOR-swizzled chunks
  float4* hsl4 = (float4*)hsl;
  const float4* hsg4 = (const float4*)(hs + (size_t)prob * Q * C);
  float* aux = ws + (size_t)PB * GT_FLOATS + (size_t)prob * AUX_FLOATS;

  // stage hs -> LDS. Chunk c4 of row r lives at slot r*64 + (c4 ^ (r>>2)).
  // Load pre-swizzled global chunk (lane^i) -> linear LDS slot (conflict-free).
#pragma unroll
  for (int i = 0; i < 16; ++i) {
    const int row = i * 4 + wv;  // row>>2 == i
    hsl4[row * 64 + lane] = hsg4[row * 64 + (lane ^ i)];
  }

  // c2_0 partials (per-wave) while staging is in flight
  {
    float c0v = cen[(size_t)prob * 2 * C + tid];
    float c1v = cen[(size_t)prob * 2 * C + C + tid];
    float p0 = wave_sum64(c0v * c0v);
    float p1 = wave_sum64(c1v * c1v);
    if (lane == 0) {
      aux[192 + wv] = p0;
      aux[196 + wv] = p1;
    }
  }
  __syncthreads();

  // ---- G: thread (ti,tj) computes 4x4 tile G[4ti+r][4tj+s]
  const int ti = tid >> 4, tj = tid & 15;
  float acc[4][4] = {};
#pragma unroll 4
  for (int c4 = 0; c4 < 64; ++c4) {
    float4 a0 = hsl4[(ti * 4 + 0) * 64 + (c4 ^ ti)];
    float4 a1 = hsl4[(ti * 4 + 1) * 64 + (c4 ^ ti)];
    float4 a2 = hsl4[(ti * 4 + 2) * 64 + (c4 ^ ti)];
    float4 a3 = hsl4[(ti * 4 + 3) * 64 + (c4 ^ ti)];
    float4 b0 = hsl4[(tj * 4 + 0) * 64 + (c4 ^ tj)];
    float4 b1 = hsl4[(tj * 4 + 1) * 64 + (c4 ^ tj)];
    float4 b2 = hsl4[(tj * 4 + 2) * 64 + (c4 ^ tj)];
    float4 b3 = hsl4[(tj * 4 + 3) * 64 + (c4 ^ tj)];
    float4 ar[4] = {a0, a1, a2, a3};
    float4 br[4] = {b0, b1, b2, b3};
#pragma unroll
    for (int r = 0; r < 4; ++r)
#pragma unroll
      for (int s = 0; s < 4; ++s)
        acc[r][s] += ar[r].x * br[s].x + ar[r].y * br[s].y +
                     ar[r].z * br[s].z + ar[r].w * br[s].w;
  }

  // write Gt: float4 slot (pb=tj)*64 + q  holds G[q][4tj..4tj+3]
  float4* gt4 = (float4*)(ws + (size_t)prob * GT_FLOATS);
#pragma unroll
  for (int r = 0; r < 4; ++r)
    gt4[tj * 64 + (ti * 4 + r)] =
        make_float4(acc[r][0], acc[r][1], acc[r][2], acc[r][3]);
  if (ti == tj) {
#pragma unroll
    for (int r = 0; r < 4; ++r) aux[128 + ti * 4 + r] = acc[r][r];
  }

  // ---- xc0 = hs . cen0 : thread = (q = tid>>2, quad cq = tid&3, 64 ch each)
  {
    const int q = tid >> 2, cq = tid & 3;
    const float4* cg4 = (const float4*)(cen + (size_t)prob * 2 * C);
    float x0 = 0.f, x1 = 0.f;
#pragma unroll
    for (int j = 0; j < 16; ++j) {
      const int c4 = cq * 16 + j;
      float4 h = hsl4[q * 64 + (c4 ^ ((q >> 2) & 15))];
      float4 k0 = cg4[c4];
      float4 k1 = cg4[64 + c4];
      x0 += h.x * k0.x + h.y * k0.y + h.z * k0.z + h.w * k0.w;
      x1 += h.x * k1.x + h.y * k1.y + h.z * k1.z + h.w * k1.w;
    }
    x0 += __shfl_xor(x0, 1);
    x0 += __shfl_xor(x0, 2);
    x1 += __shfl_xor(x1, 1);
    x1 += __shfl_xor(x1, 2);
    if (cq == 0) {
      aux[q * 2] = x0;
      aux[q * 2 + 1] = x1;
    }
  }
}

// ---------------- kernel 2: 64 sequential EM iterations, 1 wave per problem
__global__ __launch_bounds__(64, 2) void k2_iter(const float* __restrict__ hs,
                                                 const float* __restrict__ ws,
                                                 float* __restrict__ out) {
  const int prob = blockIdx.x;
  const int lane = threadIdx.x;  // = q

  __shared__ __align__(16) float a_s[2 * Q * 2];  // double-buffered a[q][k]

  const float4* gt4 = (const float4*)(ws + (size_t)prob * GT_FLOATS);
  const float* aux = ws + (size_t)PB * GT_FLOATS + (size_t)prob * AUX_FLOATS;

  float4 g[16];  // G[q][4i..4i+3]
#pragma unroll
  for (int i = 0; i < 16; ++i) g[i] = gt4[i * 64 + lane];

  const float x2 = aux[128 + lane];
  float xc0 = aux[lane * 2 + 0];
  float xc1 = aux[lane * 2 + 1];
  float c20 = aux[192] + aux[193] + aux[194] + aux[195];
  float c21 = aux[196] + aux[197] + aux[198] + aux[199];

  float a0 = 0.f, a1 = 0.f;

#pragma unroll 1
  for (int t = 0; t < Q; ++t) {
    // assignment from current (xc, c2)
    float d0 = fmaxf(x2 + c20 - 2.f * xc0, EPS_SQRT);
    float d1 = fmaxf(x2 + c21 - 2.f * xc1, EPS_SQRT);
    float t0 = sqrtf(d0), t1 = sqrtf(d1);
    float mn = fminf(t0, t1);
    float e0 = __expf(mn - t0), e1 = __expf(mn - t1);
    float inv = __builtin_amdgcn_rcpf(e0 + e1);
    a0 = e0 * inv;
    a1 = e1 * inv;
    if (t == Q - 1) break;  // final a computed; centers update done below

    float* ab = a_s + (t & 1) * 128;
    *(float2*)&ab[lane * 2] = make_float2(a0, a1);
    __syncthreads();

    // m = G . a   (lane q holds row q of G)
    const float4* a4 = (const float4*)ab;
    float m0a = 0.f, m0b = 0.f, m1a = 0.f, m1b = 0.f;
#pragma unroll
    for (int i = 0; i < 16; ++i) {
      float4 gg = g[i];
      float4 aA = a4[2 * i];      // a[4i][0],a[4i][1],a[4i+1][0],a[4i+1][1]
      float4 aB = a4[2 * i + 1];  // a[4i+2..4i+3]
      m0a = fmaf(gg.x, aA.x, m0a);
      m1a = fmaf(gg.x, aA.y, m1a);
      m0a = fmaf(gg.y, aA.z, m0a);
      m1a = fmaf(gg.y, aA.w, m1a);
      m0b = fmaf(gg.z, aB.x, m0b);
      m1b = fmaf(gg.z, aB.y, m1b);
      m0b = fmaf(gg.w, aB.z, m0b);
      m1b = fmaf(gg.w, aB.w, m1b);
    }
    float m0 = m0a + m0b, m1 = m1a + m1b;

    // den_k = sum a, s_k = a^T m  (= |num_k|^2)
    float den0 = wave_sum64(a0);
    float den1 = wave_sum64(a1);
    float s0 = wave_sum64(a0 * m0);
    float s1 = wave_sum64(a1 * m1);

    float i0 = __builtin_amdgcn_rcpf(den0 + EPS_DEN);
    float i1 = __builtin_amdgcn_rcpf(den1 + EPS_DEN);
    xc0 = m0 * i0;  // = hs_q . cen_next
    xc1 = m1 * i1;
    c20 = s0 * i0 * i0;  // = |cen_next|^2
    c21 = s1 * i1 * i1;
  }

  // ---- epilogue: centers = (a^T hs)/(den+eps); write assignment
  float* ab = a_s;
  *(float2*)&ab[lane * 2] = make_float2(a0, a1);
  __syncthreads();

  float den0 = wave_sum64(a0);
  float den1 = wave_sum64(a1);
  float i0 = __builtin_amdgcn_rcpf(den0 + EPS_DEN);
  float i1 = __builtin_amdgcn_rcpf(den1 + EPS_DEN);

  const float4* hb4 = (const float4*)(hs + (size_t)prob * Q * C);
  const float2* a2 = (const float2*)ab;
  float4 n0 = make_float4(0.f, 0.f, 0.f, 0.f);
  float4 n1 = make_float4(0.f, 0.f, 0.f, 0.f);
#pragma unroll 8
  for (int q2 = 0; q2 < Q; ++q2) {
    float4 h = hb4[q2 * 64 + lane];  // channels 4*lane..+3, coalesced
    float2 aq = a2[q2];              // uniform broadcast
    n0.x = fmaf(aq.x, h.x, n0.x);
    n0.y = fmaf(aq.x, h.y, n0.y);
    n0.z = fmaf(aq.x, h.z, n0.z);
    n0.w = fmaf(aq.x, h.w, n0.w);
    n1.x = fmaf(aq.y, h.x, n1.x);
    n1.y = fmaf(aq.y, h.y, n1.y);
    n1.z = fmaf(aq.y, h.z, n1.z);
    n1.w = fmaf(aq.y, h.w, n1.w);
  }
  float4* outc4 = (float4*)(out + (size_t)prob * 2 * C);
  outc4[lane] = make_float4(n0.x * i0, n0.y * i0, n0.z * i0, n0.w * i0);
  outc4[64 + lane] = make_float4(n1.x * i1, n1.y * i1, n1.z * i1, n1.w * i1);

  float* outa = out + (size_t)PB * 2 * C + (size_t)prob * Q * 2;
  *(float2*)&outa[lane * 2] = make_float2(a0, a1);
}

extern "C" void kernel_launch(void* const* d_in, const int* in_sizes, int n_in,
                              void* d_out, int out_size, void* d_ws,
                              size_t ws_size, hipStream_t stream) {
  const float* hs = (const float*)d_in[0];
  const float* cen = (const float*)d_in[1];
  float* out = (float*)d_out;
  float* ws = (float*)d_ws;  // needs PB*(4096+256)*4 B ~= 26.8 MB
  hipLaunchKernelGGL(k1_gram, dim3(PB), dim3(256), 0, stream, hs, cen, ws);
  hipLaunchKernelGGL(k2_iter, dim3(PB), dim3(64), 0, stream, hs, ws, out);
}

// Round 4
// 126.794 us; speedup vs baseline: 3.9875x; 1.3671x over previous
//
#include <hip/hip_runtime.h>

namespace {
constexpr int PB = 6 * 256;  // 1536 independent (l,n) problems
constexpr int Q = 64;
constexpr int C = 256;
constexpr float EPS_DEN = 1e-7f;
constexpr float EPS_SQRT = 1e-12f;
constexpr int GT_FLOATS = Q * Q;  // 4096 per problem (transposed-packed)
constexpr int AUX_FLOATS = 256;   // xc0[64][2] | x2[64] | c2 partials[8]

typedef __attribute__((ext_vector_type(8))) short bf16x8;
typedef __attribute__((ext_vector_type(4))) float f32x4;

// R2-proven full 64-lane reduction (ds_swizzle/bpermute path via __shfl_xor)
__device__ __forceinline__ float wave_sum64(float v) {
  v += __shfl_xor(v, 1);
  v += __shfl_xor(v, 2);
  v += __shfl_xor(v, 4);
  v += __shfl_xor(v, 8);
  v += __shfl_xor(v, 16);
  v += __shfl_xor(v, 32);
  return v;
}

__device__ __forceinline__ ushort bf16_rne(float x) {
  uint u = __float_as_uint(x);
  return (ushort)((u + 0x7FFFu + ((u >> 16) & 1u)) >> 16);
}
}  // namespace

// -------- kernel 1: G = H H^T via bf16-split MFMA; x2=diag(G); xc0; c2_0
__global__ __launch_bounds__(256, 2) void k1_gram(
    const float* __restrict__ hs, const float* __restrict__ cen,
    float* __restrict__ ws) {
  const int prob = blockIdx.x;
  const int tid = threadIdx.x;
  const int lane = tid & 63, w = tid >> 6;
  const int li = lane & 15, lk = lane >> 4;

  __shared__ __align__(16) ushort Hh[64 * 256];  // bf16 hi plane, swizzled
  __shared__ __align__(16) ushort Hl[64 * 256];  // bf16 lo plane, swizzled
  __shared__ __align__(16) ushort Ch[2 * 256];   // cen hi (linear)
  __shared__ __align__(16) ushort Cl[2 * 256];   // cen lo

  const float4* hsg4 = (const float4*)(hs + (size_t)prob * Q * C);
  float* gtp = ws + (size_t)prob * GT_FLOATS;
  float* aux = ws + (size_t)PB * GT_FLOATS + (size_t)prob * AUX_FLOATS;

  // ---- stage hs -> (Hh, Hl), swizzle byte ^= (row&7)<<4 within rows
#pragma unroll
  for (int i = 0; i < 16; ++i) {
    const int c = i * 256 + tid;  // float4 chunk index (coalesced)
    const int r = c >> 6, col4 = c & 63;
    float4 v = hsg4[c];
    const float x0 = v.x, x1 = v.y, x2_ = v.z, x3 = v.w;
    ushort h0 = bf16_rne(x0), h1 = bf16_rne(x1), h2 = bf16_rne(x2_),
           h3 = bf16_rne(x3);
    ushort l0 = bf16_rne(x0 - __uint_as_float((uint)h0 << 16));
    ushort l1 = bf16_rne(x1 - __uint_as_float((uint)h1 << 16));
    ushort l2 = bf16_rne(x2_ - __uint_as_float((uint)h2 << 16));
    ushort l3 = bf16_rne(x3 - __uint_as_float((uint)h3 << 16));
    const int boff = (col4 * 8) ^ ((r & 7) << 4);  // byte offset in row
    const int idx = r * 256 + (boff >> 1);
    *(ushort4*)&Hh[idx] = make_ushort4(h0, h1, h2, h3);
    *(ushort4*)&Hl[idx] = make_ushort4(l0, l1, l2, l3);
  }
  // ---- stage cen -> (Ch, Cl), linear
  if (tid < 128) {
    const float4* cg4 = (const float4*)(cen + (size_t)prob * 2 * C);
    float4 v = cg4[tid];
    ushort h0 = bf16_rne(v.x), h1 = bf16_rne(v.y), h2 = bf16_rne(v.z),
           h3 = bf16_rne(v.w);
    ushort l0 = bf16_rne(v.x - __uint_as_float((uint)h0 << 16));
    ushort l1 = bf16_rne(v.y - __uint_as_float((uint)h1 << 16));
    ushort l2 = bf16_rne(v.z - __uint_as_float((uint)h2 << 16));
    ushort l3 = bf16_rne(v.w - __uint_as_float((uint)h3 << 16));
    const int idx = (tid >> 6) * 256 + (tid & 63) * 4;
    *(ushort4*)&Ch[idx] = make_ushort4(h0, h1, h2, h3);
    *(ushort4*)&Cl[idx] = make_ushort4(l0, l1, l2, l3);
  }
  // ---- c2_0 partials (fp32 exact, from global)
  {
    float c0v = cen[(size_t)prob * 2 * C + tid];
    float c1v = cen[(size_t)prob * 2 * C + C + tid];
    float p0 = wave_sum64(c0v * c0v);
    float p1 = wave_sum64(c1v * c1v);
    if (lane == 0) {
      aux[192 + w] = p0;
      aux[196 + w] = p1;
    }
  }
  __syncthreads();

  // ---- MFMA: wave w owns tile-row ti=w, tiles (w, tj>=w); plus xc0 strip
  f32x4 acc[4] = {{0.f, 0.f, 0.f, 0.f},
                  {0.f, 0.f, 0.f, 0.f},
                  {0.f, 0.f, 0.f, 0.f},
                  {0.f, 0.f, 0.f, 0.f}};
  f32x4 accX = {0.f, 0.f, 0.f, 0.f};
  const int rA = 16 * w + li;
  const int swz = (li & 7) << 4;  // (row&7)<<4 — same for all row-blocks
#pragma unroll
  for (int kk = 0; kk < 8; ++kk) {
    const int byteA = (kk * 64 + lk * 16) ^ swz;
    const int offA = byteA >> 1;
    bf16x8 ah = *(const bf16x8*)&Hh[rA * 256 + offA];
    bf16x8 al = *(const bf16x8*)&Hl[rA * 256 + offA];
    // xc0: B = cen^T (cols 0,1 live, rest zero)
    bf16x8 cbh = {0, 0, 0, 0, 0, 0, 0, 0};
    bf16x8 cbl = {0, 0, 0, 0, 0, 0, 0, 0};
    if (li < 2) {
      const int cidx = li * 256 + kk * 32 + lk * 8;
      cbh = *(const bf16x8*)&Ch[cidx];
      cbl = *(const bf16x8*)&Cl[cidx];
    }
    accX = __builtin_amdgcn_mfma_f32_16x16x32_bf16(ah, cbh, accX, 0, 0, 0);
    accX = __builtin_amdgcn_mfma_f32_16x16x32_bf16(ah, cbl, accX, 0, 0, 0);
    accX = __builtin_amdgcn_mfma_f32_16x16x32_bf16(al, cbh, accX, 0, 0, 0);
#pragma unroll
    for (int tj = 0; tj < 4; ++tj) {
      if (tj < w) continue;  // wave-uniform skip (symmetry)
      const int rB = 16 * tj + li;
      bf16x8 bh = *(const bf16x8*)&Hh[rB * 256 + offA];  // same swizzle (li&7)
      bf16x8 bl = *(const bf16x8*)&Hl[rB * 256 + offA];
      acc[tj] =
          __builtin_amdgcn_mfma_f32_16x16x32_bf16(ah, bh, acc[tj], 0, 0, 0);
      acc[tj] =
          __builtin_amdgcn_mfma_f32_16x16x32_bf16(ah, bl, acc[tj], 0, 0, 0);
      acc[tj] =
          __builtin_amdgcn_mfma_f32_16x16x32_bf16(al, bh, acc[tj], 0, 0, 0);
    }
  }

  // ---- epilogue: scatter G (and mirror), diag -> x2, xc0
#pragma unroll
  for (int tj = 0; tj < 4; ++tj) {
    if (tj < w) continue;
#pragma unroll
    for (int r = 0; r < 4; ++r) {
      const float v = acc[tj][r];
      const int row = 16 * w + lk * 4 + r;
      const int col = 16 * tj + li;
      gtp[(col >> 2) * 256 + row * 4 + (col & 3)] = v;
      if (tj > w) gtp[(row >> 2) * 256 + col * 4 + (row & 3)] = v;
      if (row == col) aux[128 + row] = v;
    }
  }
  if (li < 2) {
#pragma unroll
    for (int r = 0; r < 4; ++r) {
      const int q = 16 * w + lk * 4 + r;
      aux[q * 2 + li] = accX[r];
    }
  }
}

// -------- kernel 2: 64 sequential EM iterations, 1 wave per problem
__global__ __launch_bounds__(64, 2) void k2_iter(const float* __restrict__ hs,
                                                 const float* __restrict__ ws,
                                                 float* __restrict__ out) {
  const int prob = blockIdx.x;
  const int lane = threadIdx.x;  // = q

  __shared__ __align__(16) float a_s[2 * Q * 2];

  const float4* gt4 = (const float4*)(ws + (size_t)prob * GT_FLOATS);
  const float* aux = ws + (size_t)PB * GT_FLOATS + (size_t)prob * AUX_FLOATS;

  float4 g[16];  // G[q][4i..4i+3]
#pragma unroll
  for (int i = 0; i < 16; ++i) g[i] = gt4[i * 64 + lane];

  const float x2 = aux[128 + lane];
  float xc0 = aux[lane * 2 + 0];
  float xc1 = aux[lane * 2 + 1];
  float c20 = aux[192] + aux[193] + aux[194] + aux[195];
  float c21 = aux[196] + aux[197] + aux[198] + aux[199];

  float a0 = 0.f, a1 = 0.f;

#pragma unroll 1
  for (int t = 0; t < Q; ++t) {
    float d0 = fmaxf(x2 + c20 - 2.f * xc0, EPS_SQRT);
    float d1 = fmaxf(x2 + c21 - 2.f * xc1, EPS_SQRT);
    float t0 = sqrtf(d0), t1 = sqrtf(d1);
    float mn = fminf(t0, t1);
    float e0 = __expf(mn - t0), e1 = __expf(mn - t1);
    float inv = __builtin_amdgcn_rcpf(e0 + e1);
    a0 = e0 * inv;
    a1 = e1 * inv;
    if (t == Q - 1) break;

    float* ab = a_s + (t & 1) * 128;
    *(float2*)&ab[lane * 2] = make_float2(a0, a1);
    // den reductions overlap the LDS broadcast round
    float den0 = wave_sum64(a0);
    float den1 = wave_sum64(a1);
    __syncthreads();

    // m = G . a  (lane q holds row q of G; a read as uniform broadcast)
    const float4* a4 = (const float4*)ab;
    float m0a = 0.f, m0b = 0.f, m1a = 0.f, m1b = 0.f;
#pragma unroll
    for (int i = 0; i < 16; ++i) {
      float4 gg = g[i];
      float4 aA = a4[2 * i];
      float4 aB = a4[2 * i + 1];
      m0a = fmaf(gg.x, aA.x, m0a);
      m1a = fmaf(gg.x, aA.y, m1a);
      m0a = fmaf(gg.y, aA.z, m0a);
      m1a = fmaf(gg.y, aA.w, m1a);
      m0b = fmaf(gg.z, aB.x, m0b);
      m1b = fmaf(gg.z, aB.y, m1b);
      m0b = fmaf(gg.w, aB.z, m0b);
      m1b = fmaf(gg.w, aB.w, m1b);
    }
    float m0 = m0a + m0b, m1 = m1a + m1b;

    float s0 = wave_sum64(a0 * m0);  // = |num_0|^2
    float s1 = wave_sum64(a1 * m1);

    float i0 = __builtin_amdgcn_rcpf(den0 + EPS_DEN);
    float i1 = __builtin_amdgcn_rcpf(den1 + EPS_DEN);
    xc0 = m0 * i0;
    xc1 = m1 * i1;
    c20 = s0 * i0 * i0;
    c21 = s1 * i1 * i1;
  }

  // ---- epilogue: centers = (a^T hs)/(den+eps); write assignment
  float* ab = a_s;
  *(float2*)&ab[lane * 2] = make_float2(a0, a1);
  __syncthreads();

  float den0 = wave_sum64(a0);
  float den1 = wave_sum64(a1);
  float i0 = __builtin_amdgcn_rcpf(den0 + EPS_DEN);
  float i1 = __builtin_amdgcn_rcpf(den1 + EPS_DEN);

  const float4* hb4 = (const float4*)(hs + (size_t)prob * Q * C);
  const float2* a2 = (const float2*)ab;
  float4 n0 = make_float4(0.f, 0.f, 0.f, 0.f);
  float4 n1 = make_float4(0.f, 0.f, 0.f, 0.f);
#pragma unroll 8
  for (int q2 = 0; q2 < Q; ++q2) {
    float4 h = hb4[q2 * 64 + lane];
    float2 aq = a2[q2];
    n0.x = fmaf(aq.x, h.x, n0.x);
    n0.y = fmaf(aq.x, h.y, n0.y);
    n0.z = fmaf(aq.x, h.z, n0.z);
    n0.w = fmaf(aq.x, h.w, n0.w);
    n1.x = fmaf(aq.y, h.x, n1.x);
    n1.y = fmaf(aq.y, h.y, n1.y);
    n1.z = fmaf(aq.y, h.z, n1.z);
    n1.w = fmaf(aq.y, h.w, n1.w);
  }
  float4* outc4 = (float4*)(out + (size_t)prob * 2 * C);
  outc4[lane] = make_float4(n0.x * i0, n0.y * i0, n0.z * i0, n0.w * i0);
  outc4[64 + lane] = make_float4(n1.x * i1, n1.y * i1, n1.z * i1, n1.w * i1);

  float* outa = out + (size_t)PB * 2 * C + (size_t)prob * Q * 2;
  *(float2*)&outa[lane * 2] = make_float2(a0, a1);
}

extern "C" void kernel_launch(void* const* d_in, const int* in_sizes, int n_in,
                              void* d_out, int out_size, void* d_ws,
                              size_t ws_size, hipStream_t stream) {
  const float* hs = (const float*)d_in[0];
  const float* cen = (const float*)d_in[1];
  float* out = (float*)d_out;
  float* ws = (float*)d_ws;  // needs PB*(4096+256)*4 B ~= 26.8 MB
  hipLaunchKernelGGL(k1_gram, dim3(PB), dim3(256), 0, stream, hs, cen, ws);
  hipLaunchKernelGGL(k2_iter, dim3(PB), dim3(64), 0, stream, hs, ws, out);
}

// Round 5
// 105.331 us; speedup vs baseline: 4.8000x; 1.2038x over previous
//
#include <hip/hip_runtime.h>

namespace {
constexpr int PB = 6 * 256;  // 1536 independent (l,n) problems
constexpr int Q = 64;
constexpr int C = 256;
constexpr float EPS_DEN = 1e-7f;
constexpr float EPS_SQRT = 1e-12f;
constexpr int GT_FLOATS = Q * Q;  // 4096 per problem (transposed-packed)
constexpr int AUX_FLOATS = 256;   // xc0[64][2] | x2[64] | c2 partials[8]

typedef __attribute__((ext_vector_type(8))) short bf16x8;
typedef __attribute__((ext_vector_type(4))) float f32x4;

// DPP row rotate-add (VALU pipe): after 1,2,4,8 all 16 lanes of a row hold
// the row sum. Proven in R1.
template <int CTRL>
__device__ __forceinline__ float ror_add(float v) {
  int r = __builtin_amdgcn_mov_dpp(__float_as_int(v), CTRL, 0xF, 0xF, true);
  return v + __int_as_float(r);
}

// Canonical GCN wave64 DPP reduction (AMD crosslane pattern):
// row sums -> row_bcast15 (row_mask 0b1010) -> row_bcast31 (row_mask 0b1100);
// lane 63 holds the total; readlane broadcasts via SGPR. VALU-only.
__device__ __forceinline__ float wave_total(float v) {
  v = ror_add<0x121>(v);  // row_ror:1
  v = ror_add<0x122>(v);  // row_ror:2
  v = ror_add<0x124>(v);  // row_ror:4
  v = ror_add<0x128>(v);  // row_ror:8
  {
    int t = __builtin_amdgcn_update_dpp(0, __float_as_int(v), 0x142, 0xA, 0xF,
                                        true);  // ROW_BCAST15, rows 1,3
    v = v + __int_as_float(t);
  }
  {
    int t = __builtin_amdgcn_update_dpp(0, __float_as_int(v), 0x143, 0xC, 0xF,
                                        true);  // ROW_BCAST31, rows 2,3
    v = v + __int_as_float(t);
  }
  return __int_as_float(__builtin_amdgcn_readlane(__float_as_int(v), 63));
}

__device__ __forceinline__ ushort bf16_rne(float x) {
  uint u = __float_as_uint(x);
  return (ushort)((u + 0x7FFFu + ((u >> 16) & 1u)) >> 16);
}
}  // namespace

// -------- kernel 1: G = H H^T via bf16-split MFMA; x2=diag(G); xc0; c2_0
// K-split: stage C in two 128-col halves -> 34 KB LDS -> multi-block/CU.
__global__ __launch_bounds__(256, 2) void k1_gram(
    const float* __restrict__ hs, const float* __restrict__ cen,
    float* __restrict__ ws) {
  const int prob = blockIdx.x;
  const int tid = threadIdx.x;
  const int lane = tid & 63, w = tid >> 6;
  const int li = lane & 15, lk = lane >> 4;

  __shared__ __align__(16) ushort Hh[64 * 128];  // bf16 hi plane (one C-half)
  __shared__ __align__(16) ushort Hl[64 * 128];  // bf16 lo plane
  __shared__ __align__(16) ushort Ch[2 * 256];   // cen hi (full C, linear)
  __shared__ __align__(16) ushort Cl[2 * 256];   // cen lo

  const float4* hsg4 = (const float4*)(hs + (size_t)prob * Q * C);
  float* gtp = ws + (size_t)prob * GT_FLOATS;
  float* aux = ws + (size_t)PB * GT_FLOATS + (size_t)prob * AUX_FLOATS;

  f32x4 acc[4] = {{0.f, 0.f, 0.f, 0.f},
                  {0.f, 0.f, 0.f, 0.f},
                  {0.f, 0.f, 0.f, 0.f},
                  {0.f, 0.f, 0.f, 0.f}};
  f32x4 accX = {0.f, 0.f, 0.f, 0.f};
  const int rA = 16 * w + li;
  const int swz = (li & 7) << 4;

#pragma unroll 1
  for (int half = 0; half < 2; ++half) {
    // ---- stage this C-half -> (Hh, Hl); row stride 128 ushorts (256 B)
#pragma unroll
    for (int i = 0; i < 8; ++i) {
      const int c = i * 256 + tid;  // 2048 chunks = 64 rows x 32 col4
      const int r = c >> 5, col4 = c & 31;
      float4 v = hsg4[r * 64 + half * 32 + col4];
      ushort h0 = bf16_rne(v.x), h1 = bf16_rne(v.y), h2 = bf16_rne(v.z),
             h3 = bf16_rne(v.w);
      ushort l0 = bf16_rne(v.x - __uint_as_float((uint)h0 << 16));
      ushort l1 = bf16_rne(v.y - __uint_as_float((uint)h1 << 16));
      ushort l2 = bf16_rne(v.z - __uint_as_float((uint)h2 << 16));
      ushort l3 = bf16_rne(v.w - __uint_as_float((uint)h3 << 16));
      const int boff = (col4 * 8) ^ ((r & 7) << 4);  // byte within 256B row
      const int idx = r * 128 + (boff >> 1);
      *(ushort4*)&Hh[idx] = make_ushort4(h0, h1, h2, h3);
      *(ushort4*)&Hl[idx] = make_ushort4(l0, l1, l2, l3);
    }
    if (half == 0) {
      // ---- stage cen (full C) and c2_0 partials
      if (tid < 128) {
        const float4* cg4 = (const float4*)(cen + (size_t)prob * 2 * C);
        float4 v = cg4[tid];
        ushort h0 = bf16_rne(v.x), h1 = bf16_rne(v.y), h2 = bf16_rne(v.z),
               h3 = bf16_rne(v.w);
        ushort l0 = bf16_rne(v.x - __uint_as_float((uint)h0 << 16));
        ushort l1 = bf16_rne(v.y - __uint_as_float((uint)h1 << 16));
        ushort l2 = bf16_rne(v.z - __uint_as_float((uint)h2 << 16));
        ushort l3 = bf16_rne(v.w - __uint_as_float((uint)h3 << 16));
        const int idx = (tid >> 6) * 256 + (tid & 63) * 4;
        *(ushort4*)&Ch[idx] = make_ushort4(h0, h1, h2, h3);
        *(ushort4*)&Cl[idx] = make_ushort4(l0, l1, l2, l3);
      }
      float c0v = cen[(size_t)prob * 2 * C + tid];
      float c1v = cen[(size_t)prob * 2 * C + C + tid];
      float p0 = wave_total(c0v * c0v);
      float p1 = wave_total(c1v * c1v);
      if (lane == 0) {
        aux[192 + w] = p0;
        aux[196 + w] = p1;
      }
    }
    __syncthreads();

    // ---- MFMA over this half's 4 K-steps
#pragma unroll
    for (int kk2 = 0; kk2 < 4; ++kk2) {
      const int kk = half * 4 + kk2;
      const int byteA = (kk2 * 64 + lk * 16) ^ swz;
      const int offA = byteA >> 1;
      bf16x8 ah = *(const bf16x8*)&Hh[rA * 128 + offA];
      bf16x8 al = *(const bf16x8*)&Hl[rA * 128 + offA];
      bf16x8 cbh = {0, 0, 0, 0, 0, 0, 0, 0};
      bf16x8 cbl = {0, 0, 0, 0, 0, 0, 0, 0};
      if (li < 2) {
        const int cidx = li * 256 + kk * 32 + lk * 8;
        cbh = *(const bf16x8*)&Ch[cidx];
        cbl = *(const bf16x8*)&Cl[cidx];
      }
      accX = __builtin_amdgcn_mfma_f32_16x16x32_bf16(ah, cbh, accX, 0, 0, 0);
      accX = __builtin_amdgcn_mfma_f32_16x16x32_bf16(ah, cbl, accX, 0, 0, 0);
      accX = __builtin_amdgcn_mfma_f32_16x16x32_bf16(al, cbh, accX, 0, 0, 0);
#pragma unroll
      for (int tj = 0; tj < 4; ++tj) {
        if (tj < w) continue;  // wave-uniform skip (symmetry)
        const int rB = 16 * tj + li;
        bf16x8 bh = *(const bf16x8*)&Hh[rB * 128 + offA];
        bf16x8 bl = *(const bf16x8*)&Hl[rB * 128 + offA];
        acc[tj] =
            __builtin_amdgcn_mfma_f32_16x16x32_bf16(ah, bh, acc[tj], 0, 0, 0);
        acc[tj] =
            __builtin_amdgcn_mfma_f32_16x16x32_bf16(ah, bl, acc[tj], 0, 0, 0);
        acc[tj] =
            __builtin_amdgcn_mfma_f32_16x16x32_bf16(al, bh, acc[tj], 0, 0, 0);
      }
    }
    __syncthreads();  // all waves done reading before restaging
  }

  // ---- epilogue: scatter G (and mirror), diag -> x2, xc0
#pragma unroll
  for (int tj = 0; tj < 4; ++tj) {
    if (tj < w) continue;
#pragma unroll
    for (int r = 0; r < 4; ++r) {
      const float v = acc[tj][r];
      const int row = 16 * w + lk * 4 + r;
      const int col = 16 * tj + li;
      gtp[(col >> 2) * 256 + row * 4 + (col & 3)] = v;
      if (tj > w) gtp[(row >> 2) * 256 + col * 4 + (row & 3)] = v;
      if (row == col) aux[128 + row] = v;
    }
  }
  if (li < 2) {
#pragma unroll
    for (int r = 0; r < 4; ++r) {
      const int q = 16 * w + lk * 4 + r;
      aux[q * 2 + li] = accX[r];
    }
  }
}

// -------- kernel 2: 64 sequential EM iterations, 1 wave per problem.
// G pinned in LDS (16 KB, chunk-XOR swizzle) — VGPR_Count=48 in R4 proved the
// compiler was re-loading G from global every iteration.
__global__ __launch_bounds__(64, 2) void k2_iter(const float* __restrict__ hs,
                                                 const float* __restrict__ ws,
                                                 float* __restrict__ out) {
  const int prob = blockIdx.x;
  const int lane = threadIdx.x;  // = q

  __shared__ __align__(16) float4 Gs[64 * 16];  // row q chunk j at j^(q&15)
  __shared__ __align__(16) float a_s[2 * Q * 2];

  const float4* gt4 = (const float4*)(ws + (size_t)prob * GT_FLOATS);
  const float* aux = ws + (size_t)PB * GT_FLOATS + (size_t)prob * AUX_FLOATS;

  // load G coalesced (gt4[j*64+q] = G[q][4j..4j+3]) -> swizzled LDS
#pragma unroll
  for (int j = 0; j < 16; ++j) {
    Gs[lane * 16 + (j ^ (lane & 15))] = gt4[j * 64 + lane];
  }

  const float x2 = aux[128 + lane];
  float xc0 = aux[lane * 2 + 0];
  float xc1 = aux[lane * 2 + 1];
  float c20 = aux[192] + aux[193] + aux[194] + aux[195];
  float c21 = aux[196] + aux[197] + aux[198] + aux[199];
  __syncthreads();

  float a0 = 0.f, a1 = 0.f;

#pragma unroll 1
  for (int t = 0; t < Q; ++t) {
    float d0 = fmaxf(x2 + c20 - 2.f * xc0, EPS_SQRT);
    float d1 = fmaxf(x2 + c21 - 2.f * xc1, EPS_SQRT);
    float t0 = __builtin_amdgcn_sqrtf(d0), t1 = __builtin_amdgcn_sqrtf(d1);
    float mn = fminf(t0, t1);
    float e0 = __expf(mn - t0), e1 = __expf(mn - t1);
    float inv = __builtin_amdgcn_rcpf(e0 + e1);
    a0 = e0 * inv;
    a1 = e1 * inv;
    if (t == Q - 1) break;

    float* ab = a_s + (t & 1) * 128;
    *(float2*)&ab[lane * 2] = make_float2(a0, a1);
    // den reductions on VALU pipe overlap the DS broadcast latency
    float den0 = wave_total(a0);
    float den1 = wave_total(a1);
    __syncthreads();

    // m = G . a  (lane q reads its swizzled LDS row; a uniform-broadcast)
    const float4* a4 = (const float4*)ab;
    float m0a = 0.f, m0b = 0.f, m1a = 0.f, m1b = 0.f;
#pragma unroll
    for (int i = 0; i < 16; ++i) {
      float4 gg = Gs[lane * 16 + (i ^ (lane & 15))];
      float4 aA = a4[2 * i];      // a[4i][0..1], a[4i+1][0..1]
      float4 aB = a4[2 * i + 1];  // a[4i+2..4i+3]
      m0a = fmaf(gg.x, aA.x, m0a);
      m1a = fmaf(gg.x, aA.y, m1a);
      m0a = fmaf(gg.y, aA.z, m0a);
      m1a = fmaf(gg.y, aA.w, m1a);
      m0b = fmaf(gg.z, aB.x, m0b);
      m1b = fmaf(gg.z, aB.y, m1b);
      m0b = fmaf(gg.w, aB.z, m0b);
      m1b = fmaf(gg.w, aB.w, m1b);
    }
    float m0 = m0a + m0b, m1 = m1a + m1b;

    float s0 = wave_total(a0 * m0);  // = |num_0|^2
    float s1 = wave_total(a1 * m1);

    float i0 = __builtin_amdgcn_rcpf(den0 + EPS_DEN);
    float i1 = __builtin_amdgcn_rcpf(den1 + EPS_DEN);
    xc0 = m0 * i0;
    xc1 = m1 * i1;
    c20 = s0 * i0 * i0;
    c21 = s1 * i1 * i1;
  }

  // ---- epilogue: centers = (a^T hs)/(den+eps); write assignment
  float* ab = a_s;
  *(float2*)&ab[lane * 2] = make_float2(a0, a1);
  float den0 = wave_total(a0);
  float den1 = wave_total(a1);
  __syncthreads();
  float i0 = __builtin_amdgcn_rcpf(den0 + EPS_DEN);
  float i1 = __builtin_amdgcn_rcpf(den1 + EPS_DEN);

  const float4* hb4 = (const float4*)(hs + (size_t)prob * Q * C);
  const float2* a2 = (const float2*)ab;
  float4 n0 = make_float4(0.f, 0.f, 0.f, 0.f);
  float4 n1 = make_float4(0.f, 0.f, 0.f, 0.f);
#pragma unroll 8
  for (int q2 = 0; q2 < Q; ++q2) {
    float4 h = hb4[q2 * 64 + lane];
    float2 aq = a2[q2];
    n0.x = fmaf(aq.x, h.x, n0.x);
    n0.y = fmaf(aq.x, h.y, n0.y);
    n0.z = fmaf(aq.x, h.z, n0.z);
    n0.w = fmaf(aq.x, h.w, n0.w);
    n1.x = fmaf(aq.y, h.x, n1.x);
    n1.y = fmaf(aq.y, h.y, n1.y);
    n1.z = fmaf(aq.y, h.z, n1.z);
    n1.w = fmaf(aq.y, h.w, n1.w);
  }
  float4* outc4 = (float4*)(out + (size_t)prob * 2 * C);
  outc4[lane] = make_float4(n0.x * i0, n0.y * i0, n0.z * i0, n0.w * i0);
  outc4[64 + lane] = make_float4(n1.x * i1, n1.y * i1, n1.z * i1, n1.w * i1);

  float* outa = out + (size_t)PB * 2 * C + (size_t)prob * Q * 2;
  *(float2*)&outa[lane * 2] = make_float2(a0, a1);
}

extern "C" void kernel_launch(void* const* d_in, const int* in_sizes, int n_in,
                              void* d_out, int out_size, void* d_ws,
                              size_t ws_size, hipStream_t stream) {
  const float* hs = (const float*)d_in[0];
  const float* cen = (const float*)d_in[1];
  float* out = (float*)d_out;
  float* ws = (float*)d_ws;  // needs PB*(4096+256)*4 B ~= 26.8 MB
  hipLaunchKernelGGL(k1_gram, dim3(PB), dim3(256), 0, stream, hs, cen, ws);
  hipLaunchKernelGGL(k2_iter, dim3(PB), dim3(64), 0, stream, hs, ws, out);
}